// Round 5
// baseline (349.809 us; speedup 1.0000x reference)
//
#include <hip/hip_runtime.h>

// LSTM(units=64) over T=5, D_IN=1, then Dense(1, relu).
// R18 = R16 math, block THINNED 2x for occupancy: MB=64, 1 row-group,
// grid 4096, LDS 38.9 -> 19.9 KB.
// MODEL (R14-R17 counters): single VALU pipe, exp2/rcp at ~16cyc/instr
// vs 2 for pk-f32.  Busy-time tracks instr cuts (R13 63.6 -> R16 56us)
// but wall pinned at ~86 by ~30us IDLE (35%) -- wave starvation: LDS
// 38912B capped ~3 blocks/CU (~3 waves/SIMD) while VGPR=84 allows 6.
// R18: halve LDS/block -> 6 blocks/CU (75% occ) at VGPR<=85
// (launch_bounds(256,6)).  Cost: U-staging amortizes over 20 tiles not
// 40 (+~3% busy, R9-measured) -- buys 2x latency hiding.
// Math (R16, verified): packed-fp32 pairs, fma-folded exp2 algebra,
// cs=CSC*c carried state, 4-wide batched rcp w/ exact 2^-k scale fold:
//   site1 k=30: 4-prod in [2^-120,2^120.8] (bound pq<=2^60.2, R14/R15-
//   verified on HW), site2 k=9: [2^-36,2^102.4].  5 exp2 + 0.5 rcp per
//   cell = algebraic floor.
// Survey: remat+exp2 algebra 133->102; packed pairs ->95.8; MB parabola
// (issue-bound era) 64/128/256 = 95.8/93.0/109; paired rcp 93->91.2;
// fma-fold+batch 91.2->85.9; 4-wide rcp flat (latency/throughput
// cancel) -> idle is the floor, hence this round.
// Falsification: occ up + wall flat -> barrier-structural idle ->
// stripe-parity barrier merge next.  Scratch>0 -> rerun bound (256,4).
// absmax: exactly 1.953125e-3 (f16 h round-trip quantization).

typedef _Float16 f16x8 __attribute__((ext_vector_type(8)));
typedef float f32x4 __attribute__((ext_vector_type(4)));
typedef float f32x2 __attribute__((ext_vector_type(2)));

#define MB 64        // rows per block (1 group)
#define NTHREADS 256
#define HSTR 68

__device__ __forceinline__ float ex2(float x) { return __builtin_amdgcn_exp2f(x); }
__device__ __forceinline__ float rcp(float x) { return __builtin_amdgcn_rcpf(x); }
__device__ __forceinline__ f32x2 fma2(f32x2 a, f32x2 b, f32x2 c) {
    return __builtin_elementwise_fma(a, b, c);
}
__device__ __forceinline__ f32x2 ex22(f32x2 a) {
    return (f32x2){ex2(a.x), ex2(a.y)};
}

__global__ __launch_bounds__(NTHREADS, 6) void lstm_fused(
    const float* __restrict__ x,   // [B,5,1]
    const float* __restrict__ W,   // [1,256]  gate order i,f,g,o
    const float* __restrict__ U,   // [64,256]
    const float* __restrict__ b,   // [256]
    const float* __restrict__ Wd,  // [64,1]
    const float* __restrict__ bd,  // [1]
    float* __restrict__ out,       // [B,1]
    int B)
{
    __shared__ _Float16 hbuf[2][64 * HSTR];     // [parity] 17.0 KB
    __shared__ float xs[5][MB];                 // 1.25 KB, [t][row]
    __shared__ float red[4][MB];                // 1 KB
    __shared__ float wds[64];                   // 0.25 KB

    const int tid  = threadIdx.x;
    const int wv   = tid >> 6;
    const int lane = tid & 63;
    const int l15  = lane & 15;
    const int quad = lane >> 4;
    const int row0 = blockIdx.x * MB;

    // stage x transposed to [t][row]; stage Wd
    for (int i = tid; i < MB * 5; i += NTHREADS)
        xs[i % 5][i / 5] = x[row0 * 5 + i];
    if (tid < 64) wds[tid] = Wd[tid];

    const float LOG2E = 1.44269504f;
    const float gscale[4] = {-LOG2E, -LOG2E, -2.0f * LOG2E, -LOG2E};
    const float CSC = -2.0f * LOG2E;
    // scaled constants (exact powers of 2 folded in)
    const f32x2 K30  = {0x1p-30f, 0x1p-30f};
    const f32x2 C30  = {CSC * 0x1p-30f, CSC * 0x1p-30f};
    const f32x2 NC30 = {-CSC * 0x1p-30f, -CSC * 0x1p-30f};
    const f32x2 K9   = {0x1p-9f, 0x1p-9f};
    const f32x2 NK9  = {-0x1p-9f, -0x1p-9f};

    // U B-fragments loaded ONCE (n = gate*64 + wv*16 + l15,
    // k = kh*32 + quad*8 + j), scaled, cvt f16, pinned vs remat.
    const int ncol = wv * 16 + l15;
    float Wf[4], bf[4];
    f16x8 Bf[4][2];
#pragma unroll
    for (int g = 0; g < 4; ++g) {
        const int n = g * 64 + ncol;
        const float s = gscale[g];
        Wf[g] = W[n] * s;
        bf[g] = b[n] * s;
#pragma unroll
        for (int kh = 0; kh < 2; ++kh) {
            f16x8 v;
#pragma unroll
            for (int j = 0; j < 8; ++j) {
                const int k = kh * 32 + quad * 8 + j;
                v[j] = (_Float16)(U[k * 256 + n] * s);
            }
            Bf[g][kh] = v;
            asm volatile("" : "+v"(Bf[g][kh]));
        }
    }

    // cell state cs = CSC * c: [rt][pair], pair pr covers rows quad*4+2pr+{0,1}
    f32x2 cst[4][2];
#pragma unroll
    for (int a = 0; a < 4; ++a)
#pragma unroll
        for (int pr = 0; pr < 2; ++pr) cst[a][pr] = (f32x2){0.f, 0.f};

    __syncthreads();  // xs visible

    // ---- t = 0 (h=0, c=0): c = i*g, h = o*tanh(c) ----
#pragma unroll
    for (int rtp = 0; rtp < 2; ++rtp) {
        const int rtA = 2 * rtp, rtB = 2 * rtp + 1;
        const f32x4 xvA = *(const f32x4*)&xs[0][rtA * 16 + quad * 4];
        const f32x4 xvB = *(const f32x4*)&xs[0][rtB * 16 + quad * 4];
        const f32x2 wi = {Wf[0], Wf[0]}, bi = {bf[0], bf[0]};
        const f32x2 wg = {Wf[2], Wf[2]}, bg = {bf[2], bf[2]};
        const f32x2 wo = {Wf[3], Wf[3]}, bo = {bf[3], bf[3]};
        const f32x2 xA0 = {xvA[0], xvA[1]}, xA1 = {xvA[2], xvA[3]};
        const f32x2 xB0 = {xvB[0], xvB[1]}, xB1 = {xvB[2], xvB[3]};
        const f32x2 eiA0 = ex22(fma2(xA0, wi, bi));
        const f32x2 eiA1 = ex22(fma2(xA1, wi, bi));
        const f32x2 eiB0 = ex22(fma2(xB0, wi, bi));
        const f32x2 eiB1 = ex22(fma2(xB1, wi, bi));
        const f32x2 egA0 = ex22(fma2(xA0, wg, bg));
        const f32x2 egA1 = ex22(fma2(xA1, wg, bg));
        const f32x2 egB0 = ex22(fma2(xB0, wg, bg));
        const f32x2 egB1 = ex22(fma2(xB1, wg, bg));
        const f32x2 eoA0 = ex22(fma2(xA0, wo, bo));
        const f32x2 eoA1 = ex22(fma2(xA1, wo, bo));
        const f32x2 eoB0 = ex22(fma2(xB0, wo, bo));
        const f32x2 eoB1 = ex22(fma2(xB1, wo, bo));
        // site1 (q=1 at t0), scaled 2^-30
        const f32x2 PA0 = fma2(eiA0, K30, K30), PA1 = fma2(eiA1, K30, K30);
        const f32x2 PB0 = fma2(eiB0, K30, K30), PB1 = fma2(eiB1, K30, K30);
        const f32x2 pA0 = fma2(egA0, PA0, PA0), pA1 = fma2(egA1, PA1, PA1);
        const f32x2 pB0 = fma2(egB0, PB0, PB0), pB1 = fma2(egB1, PB1, PB1);
        const f32x2 wsA0 = fma2(egA0, NC30, C30), wsA1 = fma2(egA1, NC30, C30);
        const f32x2 wsB0 = fma2(egB0, NC30, C30), wsB1 = fma2(egB1, NC30, C30);
        const f32x2 mA = pA0 * pA1, mB = pB0 * pB1;
        const f32x2 M  = mA * mB;
        const f32x2 r  = {rcp(M.x), rcp(M.y)};
        const f32x2 rA = r * mB, rB = r * mA;
        const f32x2 csA0 = wsA0 * (rA * pA1);
        const f32x2 csA1 = wsA1 * (rA * pA0);
        const f32x2 csB0 = wsB0 * (rB * pB1);
        const f32x2 csB1 = wsB1 * (rB * pB0);
        cst[rtA][0] = csA0; cst[rtA][1] = csA1;
        cst[rtB][0] = csB0; cst[rtB][1] = csB1;
        const f32x2 ecA0 = ex22(csA0), ecA1 = ex22(csA1);
        const f32x2 ecB0 = ex22(csB0), ecB1 = ex22(csB1);
        // site2, scaled 2^-9
        const f32x2 AoA0 = fma2(eoA0, K9, K9), AoA1 = fma2(eoA1, K9, K9);
        const f32x2 AoB0 = fma2(eoB0, K9, K9), AoB1 = fma2(eoB1, K9, K9);
        const f32x2 dnA0 = fma2(ecA0, AoA0, AoA0), dnA1 = fma2(ecA1, AoA1, AoA1);
        const f32x2 dnB0 = fma2(ecB0, AoB0, AoB0), dnB1 = fma2(ecB1, AoB1, AoB1);
        const f32x2 omA0 = fma2(ecA0, NK9, K9), omA1 = fma2(ecA1, NK9, K9);
        const f32x2 omB0 = fma2(ecB0, NK9, K9), omB1 = fma2(ecB1, NK9, K9);
        const f32x2 m2A = dnA0 * dnA1, m2B = dnB0 * dnB1;
        const f32x2 M2  = m2A * m2B;
        const f32x2 r2  = {rcp(M2.x), rcp(M2.y)};
        const f32x2 r2A = r2 * m2B, r2B = r2 * m2A;
        const f32x2 hA0 = omA0 * (r2A * dnA1);
        const f32x2 hA1 = omA1 * (r2A * dnA0);
        const f32x2 hB0 = omB0 * (r2B * dnB1);
        const f32x2 hB1 = omB1 * (r2B * dnB0);
        const int rbA = rtA * 16 + quad * 4;
        const int rbB = rtB * 16 + quad * 4;
        hbuf[0][(rbA + 0) * HSTR + ncol] = (_Float16)hA0.x;
        hbuf[0][(rbA + 1) * HSTR + ncol] = (_Float16)hA0.y;
        hbuf[0][(rbA + 2) * HSTR + ncol] = (_Float16)hA1.x;
        hbuf[0][(rbA + 3) * HSTR + ncol] = (_Float16)hA1.y;
        hbuf[0][(rbB + 0) * HSTR + ncol] = (_Float16)hB0.x;
        hbuf[0][(rbB + 1) * HSTR + ncol] = (_Float16)hB0.y;
        hbuf[0][(rbB + 2) * HSTR + ncol] = (_Float16)hB1.x;
        hbuf[0][(rbB + 3) * HSTR + ncol] = (_Float16)hB1.y;
    }

    // ---- t = 1..4 ----
#pragma unroll
    for (int t = 1; t < 5; ++t) {
        const int src = (t + 1) & 1;
        const int dst = t & 1;
        __syncthreads();
#pragma unroll
        for (int rtp = 0; rtp < 2; ++rtp) {
            const int rtA = 2 * rtp, rtB = 2 * rtp + 1;
            const int arowA = rtA * 16 + l15;   // A layout: m = lane&15
            const int arowB = rtB * 16 + l15;
            const f16x8 a0A = *(const f16x8*)&hbuf[src][arowA * HSTR + quad * 8];
            const f16x8 a1A = *(const f16x8*)&hbuf[src][arowA * HSTR + 32 + quad * 8];
            const f16x8 a0B = *(const f16x8*)&hbuf[src][arowB * HSTR + quad * 8];
            const f16x8 a1B = *(const f16x8*)&hbuf[src][arowB * HSTR + 32 + quad * 8];
            const f32x4 xvA = *(const f32x4*)&xs[t][rtA * 16 + quad * 4];
            const f32x4 xvB = *(const f32x4*)&xs[t][rtB * 16 + quad * 4];
            const f32x2 xloA = {xvA[0], xvA[1]}, xhiA = {xvA[2], xvA[3]};
            const f32x2 xloB = {xvB[0], xvB[1]}, xhiB = {xvB[2], xvB[3]};
            f32x4 accA[4], accB[4];
#pragma unroll
            for (int g = 0; g < 4; ++g) {
                const f32x2 wgv = {Wf[g], Wf[g]};
                const f32x2 bgv = {bf[g], bf[g]};
                const f32x2 zloA = fma2(xloA, wgv, bgv);
                const f32x2 zhiA = fma2(xhiA, wgv, bgv);
                f32x4 zA = {zloA.x, zloA.y, zhiA.x, zhiA.y};
                zA = __builtin_amdgcn_mfma_f32_16x16x32_f16(a0A, Bf[g][0], zA, 0, 0, 0);
                zA = __builtin_amdgcn_mfma_f32_16x16x32_f16(a1A, Bf[g][1], zA, 0, 0, 0);
                accA[g] = zA;
                const f32x2 zloB = fma2(xloB, wgv, bgv);
                const f32x2 zhiB = fma2(xhiB, wgv, bgv);
                f32x4 zB = {zloB.x, zloB.y, zhiB.x, zhiB.y};
                zB = __builtin_amdgcn_mfma_f32_16x16x32_f16(a0B, Bf[g][0], zB, 0, 0, 0);
                zB = __builtin_amdgcn_mfma_f32_16x16x32_f16(a1B, Bf[g][1], zB, 0, 0, 0);
                accB[g] = zB;
            }
            // 32 independent gate exp2s
            const f32x2 eiA0 = {ex2(accA[0][0]), ex2(accA[0][1])};
            const f32x2 eiA1 = {ex2(accA[0][2]), ex2(accA[0][3])};
            const f32x2 efA0 = {ex2(accA[1][0]), ex2(accA[1][1])};
            const f32x2 efA1 = {ex2(accA[1][2]), ex2(accA[1][3])};
            const f32x2 egA0 = {ex2(accA[2][0]), ex2(accA[2][1])};
            const f32x2 egA1 = {ex2(accA[2][2]), ex2(accA[2][3])};
            const f32x2 eoA0 = {ex2(accA[3][0]), ex2(accA[3][1])};
            const f32x2 eoA1 = {ex2(accA[3][2]), ex2(accA[3][3])};
            const f32x2 eiB0 = {ex2(accB[0][0]), ex2(accB[0][1])};
            const f32x2 eiB1 = {ex2(accB[0][2]), ex2(accB[0][3])};
            const f32x2 efB0 = {ex2(accB[1][0]), ex2(accB[1][1])};
            const f32x2 efB1 = {ex2(accB[1][2]), ex2(accB[1][3])};
            const f32x2 egB0 = {ex2(accB[2][0]), ex2(accB[2][1])};
            const f32x2 egB1 = {ex2(accB[2][2]), ex2(accB[2][3])};
            const f32x2 eoB0 = {ex2(accB[3][0]), ex2(accB[3][1])};
            const f32x2 eoB1 = {ex2(accB[3][2]), ex2(accB[3][3])};
            // site1 scaled 2^-30
            const f32x2 PA0 = fma2(eiA0, K30, K30), PA1 = fma2(eiA1, K30, K30);
            const f32x2 PB0 = fma2(eiB0, K30, K30), PB1 = fma2(eiB1, K30, K30);
            const f32x2 pA0 = fma2(egA0, PA0, PA0), pA1 = fma2(egA1, PA1, PA1);
            const f32x2 pB0 = fma2(egB0, PB0, PB0), pB1 = fma2(egB1, PB1, PB1);
            const f32x2 wsA0 = fma2(egA0, NC30, C30), wsA1 = fma2(egA1, NC30, C30);
            const f32x2 wsB0 = fma2(egB0, NC30, C30), wsB1 = fma2(egB1, NC30, C30);
            const f32x2 qwA0 = fma2(efA0, wsA0, wsA0), qwA1 = fma2(efA1, wsA1, wsA1);
            const f32x2 qwB0 = fma2(efB0, wsB0, wsB0), qwB1 = fma2(efB1, wsB1, wsB1);
            const f32x2 pqA0 = fma2(efA0, pA0, pA0), pqA1 = fma2(efA1, pA1, pA1);
            const f32x2 pqB0 = fma2(efB0, pB0, pB0), pqB1 = fma2(efB1, pB1, pB1);
            const f32x2 numsA0 = fma2(cst[rtA][0], pA0, qwA0);
            const f32x2 numsA1 = fma2(cst[rtA][1], pA1, qwA1);
            const f32x2 numsB0 = fma2(cst[rtB][0], pB0, qwB0);
            const f32x2 numsB1 = fma2(cst[rtB][1], pB1, qwB1);
            const f32x2 mA = pqA0 * pqA1, mB = pqB0 * pqB1;
            const f32x2 M  = mA * mB;
            const f32x2 r  = {rcp(M.x), rcp(M.y)};
            const f32x2 rA = r * mB, rB = r * mA;
            const f32x2 csA0 = numsA0 * (rA * pqA1);
            const f32x2 csA1 = numsA1 * (rA * pqA0);
            const f32x2 csB0 = numsB0 * (rB * pqB1);
            const f32x2 csB1 = numsB1 * (rB * pqB0);
            cst[rtA][0] = csA0; cst[rtA][1] = csA1;
            cst[rtB][0] = csB0; cst[rtB][1] = csB1;
            const f32x2 ecA0 = ex22(csA0), ecA1 = ex22(csA1);
            const f32x2 ecB0 = ex22(csB0), ecB1 = ex22(csB1);
            // site2 scaled 2^-9
            const f32x2 AoA0 = fma2(eoA0, K9, K9), AoA1 = fma2(eoA1, K9, K9);
            const f32x2 AoB0 = fma2(eoB0, K9, K9), AoB1 = fma2(eoB1, K9, K9);
            const f32x2 dnA0 = fma2(ecA0, AoA0, AoA0), dnA1 = fma2(ecA1, AoA1, AoA1);
            const f32x2 dnB0 = fma2(ecB0, AoB0, AoB0), dnB1 = fma2(ecB1, AoB1, AoB1);
            const f32x2 omA0 = fma2(ecA0, NK9, K9), omA1 = fma2(ecA1, NK9, K9);
            const f32x2 omB0 = fma2(ecB0, NK9, K9), omB1 = fma2(ecB1, NK9, K9);
            const f32x2 m2A = dnA0 * dnA1, m2B = dnB0 * dnB1;
            const f32x2 M2  = m2A * m2B;
            const f32x2 r2  = {rcp(M2.x), rcp(M2.y)};
            const f32x2 r2A = r2 * m2B, r2B = r2 * m2A;
            const f32x2 hA0 = omA0 * (r2A * dnA1);
            const f32x2 hA1 = omA1 * (r2A * dnA0);
            const f32x2 hB0 = omB0 * (r2B * dnB1);
            const f32x2 hB1 = omB1 * (r2B * dnB0);
            const int rbA = rtA * 16 + quad * 4;
            const int rbB = rtB * 16 + quad * 4;
            hbuf[dst][(rbA + 0) * HSTR + ncol] = (_Float16)hA0.x;
            hbuf[dst][(rbA + 1) * HSTR + ncol] = (_Float16)hA0.y;
            hbuf[dst][(rbA + 2) * HSTR + ncol] = (_Float16)hA1.x;
            hbuf[dst][(rbA + 3) * HSTR + ncol] = (_Float16)hA1.y;
            hbuf[dst][(rbB + 0) * HSTR + ncol] = (_Float16)hB0.x;
            hbuf[dst][(rbB + 1) * HSTR + ncol] = (_Float16)hB0.y;
            hbuf[dst][(rbB + 2) * HSTR + ncol] = (_Float16)hB1.x;
            hbuf[dst][(rbB + 3) * HSTR + ncol] = (_Float16)hB1.y;
        }
    }

    __syncthreads();  // h(t=4) complete in hbuf[0]

    // Dense(1, relu): 4 threads per row, each sums 16 of the 64 units.
    {
        const int row = tid & 63;           // 0..63
        const int qh  = tid >> 6;           // 0..3
        float s = 0.0f;
#pragma unroll
        for (int j = 0; j < 16; ++j)
            s += (float)hbuf[0][row * HSTR + qh * 16 + j] * wds[qh * 16 + j];
        red[qh][row] = s;
    }
    __syncthreads();
    if (tid < MB) {
        const float r = red[0][tid] + red[1][tid] + red[2][tid] + red[3][tid] + bd[0];
        out[row0 + tid] = fmaxf(r, 0.0f);
    }
}

extern "C" void kernel_launch(void* const* d_in, const int* in_sizes, int n_in,
                              void* d_out, int out_size, void* d_ws, size_t ws_size,
                              hipStream_t stream) {
    const float* x  = (const float*)d_in[0];
    const float* W  = (const float*)d_in[1];
    const float* U  = (const float*)d_in[2];
    const float* b  = (const float*)d_in[3];
    const float* Wd = (const float*)d_in[4];
    const float* bd = (const float*)d_in[5];
    float* out = (float*)d_out;
    const int B = in_sizes[0] / 5;
    const int grid = B / MB;   // 4096 blocks
    lstm_fused<<<grid, NTHREADS, 0, stream>>>(x, W, U, b, Wd, bd, out, B);
}

// Round 6
// 135.186 us; speedup vs baseline: 2.5876x; 2.5876x over previous
//
#include <hip/hip_runtime.h>

// LSTM(units=64) over T=5, D_IN=1, then Dense(1, relu).
// R19 = occupancy retest at a FEASIBLE register budget.
// R18 post-mortem: (256,6) forced total-regs<=85 vs ~148 live
// (84 arch-VGPR + ~64 AGPR, unified file) -> VGPR 40, 1.25GB/dispatch
// scratch traffic, 296us.  Occupancy DID rise 28->61% -- starvation
// theory untested, allocator was the failure.  This round shrinks the
// live set instead of squeezing it:
//  - MB=64 thin block (cst halved, LDS 38.9->19.9 KB, 8 blocks LDS-able)
//  - revert R16 rt-pair fusion -> R15 per-tile math (verified 85.9us
//    algebra; frees ~16 temp + 16 acc regs; R16 was flat anyway)
//  - launch_bounds(256,4): cap 128 >= ~100 est. need -> no spill,
//    4 blocks/CU x 4 waves = 16 waves/CU (champion: 12).
// Sentinels: FETCH ~3MB / WRITE ~1MB (scratch=0), VGPR 70-85, LDS 19968.
// Predict: occ 28->45-55%, VALUBusy 65->73-82%, dur 86 -> 68-78us.
// Falsify: occ up + dur flat -> idle is barrier-structural -> revert to
// R16 champion (MB=128, (256,3)) and attack barrier structure.
// Math (R15, HW-verified): packed-fp32 pairs, fma-folded exp2 algebra,
// cs=CSC*c carried state, 2-wide batched rcp (bound pq<=2^60.2 ->
// products <=2^120.4, hard-safe):
//   p=(1+ei)(1+eg), pq=fma(ef,p,p):  cs' = (cs*p + qw) * rcp(pq)
//   h = om * rcp(dn),  dn=fma(ec,Ao,Ao), ec=exp2(cs')
// 5 exp2 + 1 rcp per cell.  absmax: exactly 1.953125e-3.

typedef _Float16 f16x8 __attribute__((ext_vector_type(8)));
typedef float f32x4 __attribute__((ext_vector_type(4)));
typedef float f32x2 __attribute__((ext_vector_type(2)));

#define MB 64        // rows per block (1 group)
#define NTHREADS 256
#define HSTR 68

__device__ __forceinline__ float ex2(float x) { return __builtin_amdgcn_exp2f(x); }
__device__ __forceinline__ float rcp(float x) { return __builtin_amdgcn_rcpf(x); }
__device__ __forceinline__ f32x2 fma2(f32x2 a, f32x2 b, f32x2 c) {
    return __builtin_elementwise_fma(a, b, c);
}
__device__ __forceinline__ f32x2 ex22(f32x2 a) {
    return (f32x2){ex2(a.x), ex2(a.y)};
}

__global__ __launch_bounds__(NTHREADS, 4) void lstm_fused(
    const float* __restrict__ x,   // [B,5,1]
    const float* __restrict__ W,   // [1,256]  gate order i,f,g,o
    const float* __restrict__ U,   // [64,256]
    const float* __restrict__ b,   // [256]
    const float* __restrict__ Wd,  // [64,1]
    const float* __restrict__ bd,  // [1]
    float* __restrict__ out,       // [B,1]
    int B)
{
    __shared__ _Float16 hbuf[2][64 * HSTR];     // [parity] 17.0 KB
    __shared__ float xs[5][MB];                 // 1.25 KB, [t][row]
    __shared__ float red[4][MB];                // 1 KB
    __shared__ float wds[64];                   // 0.25 KB

    const int tid  = threadIdx.x;
    const int wv   = tid >> 6;
    const int lane = tid & 63;
    const int l15  = lane & 15;
    const int quad = lane >> 4;
    const int row0 = blockIdx.x * MB;

    // stage x transposed to [t][row]; stage Wd
    for (int i = tid; i < MB * 5; i += NTHREADS)
        xs[i % 5][i / 5] = x[row0 * 5 + i];
    if (tid < 64) wds[tid] = Wd[tid];

    const float LOG2E = 1.44269504f;
    const float gscale[4] = {-LOG2E, -LOG2E, -2.0f * LOG2E, -LOG2E};
    const float CSC = -2.0f * LOG2E;
    const f32x2 CSC2  = {CSC, CSC};
    const f32x2 NCSC2 = {-CSC, -CSC};

    // U B-fragments loaded ONCE (n = gate*64 + wv*16 + l15,
    // k = kh*32 + quad*8 + j), scaled, cvt f16, pinned vs remat.
    const int ncol = wv * 16 + l15;
    float Wf[4], bf[4];
    f16x8 Bf[4][2];
#pragma unroll
    for (int g = 0; g < 4; ++g) {
        const int n = g * 64 + ncol;
        const float s = gscale[g];
        Wf[g] = W[n] * s;
        bf[g] = b[n] * s;
#pragma unroll
        for (int kh = 0; kh < 2; ++kh) {
            f16x8 v;
#pragma unroll
            for (int j = 0; j < 8; ++j) {
                const int k = kh * 32 + quad * 8 + j;
                v[j] = (_Float16)(U[k * 256 + n] * s);
            }
            Bf[g][kh] = v;
            asm volatile("" : "+v"(Bf[g][kh]));
        }
    }

    // cell state cs = CSC * c: [rt][pair], pair pr covers rows quad*4+2pr+{0,1}
    f32x2 cst[4][2];
#pragma unroll
    for (int a = 0; a < 4; ++a)
#pragma unroll
        for (int pr = 0; pr < 2; ++pr) cst[a][pr] = (f32x2){0.f, 0.f};

    __syncthreads();  // xs visible

    // ---- t = 0 (h=0, c=0): c = i*g, h = o*tanh(c) ----
#pragma unroll
    for (int rt = 0; rt < 4; ++rt) {
        const f32x4 xv = *(const f32x4*)&xs[0][rt * 16 + quad * 4];
        const f32x2 xp0 = {xv[0], xv[1]};
        const f32x2 xp1 = {xv[2], xv[3]};
        const f32x2 wi = {Wf[0], Wf[0]}, bi = {bf[0], bf[0]};
        const f32x2 wg = {Wf[2], Wf[2]}, bg = {bf[2], bf[2]};
        const f32x2 wo = {Wf[3], Wf[3]}, bo = {bf[3], bf[3]};
        const f32x2 ei0 = ex22(fma2(xp0, wi, bi));
        const f32x2 ei1 = ex22(fma2(xp1, wi, bi));
        const f32x2 eg0 = ex22(fma2(xp0, wg, bg));
        const f32x2 eg1 = ex22(fma2(xp1, wg, bg));
        const f32x2 eo0 = ex22(fma2(xp0, wo, bo));
        const f32x2 eo1 = ex22(fma2(xp1, wo, bo));
        // site1 (q=1 at t0): p = (1+ei)(1+eg)
        const f32x2 P0 = ei0 + 1.0f;
        const f32x2 P1 = ei1 + 1.0f;
        const f32x2 p0 = fma2(eg0, P0, P0);
        const f32x2 p1 = fma2(eg1, P1, P1);
        const f32x2 w0 = fma2(eg0, NCSC2, CSC2);   // CSC*(1-eg)
        const f32x2 w1 = fma2(eg1, NCSC2, CSC2);
        const f32x2 m1 = p0 * p1;
        const f32x2 r1 = {rcp(m1.x), rcp(m1.y)};
        const f32x2 cs0 = w0 * (r1 * p1);          // CSC * (i*g)
        const f32x2 cs1 = w1 * (r1 * p0);
        cst[rt][0] = cs0;
        cst[rt][1] = cs1;
        const f32x2 ec0 = ex22(cs0);
        const f32x2 ec1 = ex22(cs1);
        const f32x2 Ao0 = eo0 + 1.0f;
        const f32x2 Ao1 = eo1 + 1.0f;
        const f32x2 dn0 = fma2(ec0, Ao0, Ao0);
        const f32x2 dn1 = fma2(ec1, Ao1, Ao1);
        const f32x2 om0 = 1.0f - ec0;
        const f32x2 om1 = 1.0f - ec1;
        const f32x2 m2 = dn0 * dn1;
        const f32x2 r2 = {rcp(m2.x), rcp(m2.y)};
        const f32x2 h20 = om0 * (r2 * dn1);
        const f32x2 h21 = om1 * (r2 * dn0);
        const int rb = rt * 16 + quad * 4;
        hbuf[0][(rb + 0) * HSTR + ncol] = (_Float16)h20.x;
        hbuf[0][(rb + 1) * HSTR + ncol] = (_Float16)h20.y;
        hbuf[0][(rb + 2) * HSTR + ncol] = (_Float16)h21.x;
        hbuf[0][(rb + 3) * HSTR + ncol] = (_Float16)h21.y;
    }

    // ---- t = 1..4 ----
#pragma unroll
    for (int t = 1; t < 5; ++t) {
        const int src = (t + 1) & 1;
        const int dst = t & 1;
        __syncthreads();
#pragma unroll
        for (int rt = 0; rt < 4; ++rt) {
            const int arow = rt * 16 + l15;   // A layout: m = lane&15
            const f16x8 a0 = *(const f16x8*)&hbuf[src][arow * HSTR + quad * 8];
            const f16x8 a1 = *(const f16x8*)&hbuf[src][arow * HSTR + 32 + quad * 8];
            const f32x4 xv = *(const f32x4*)&xs[t][rt * 16 + quad * 4];
            const f32x2 xlo = {xv[0], xv[1]};
            const f32x2 xhi = {xv[2], xv[3]};
            f32x4 acc[4];
#pragma unroll
            for (int g = 0; g < 4; ++g) {
                const f32x2 wgv = {Wf[g], Wf[g]};
                const f32x2 bgv = {bf[g], bf[g]};
                const f32x2 zlo = fma2(xlo, wgv, bgv);
                const f32x2 zhi = fma2(xhi, wgv, bgv);
                f32x4 z = {zlo.x, zlo.y, zhi.x, zhi.y};
                z = __builtin_amdgcn_mfma_f32_16x16x32_f16(a0, Bf[g][0], z, 0, 0, 0);
                z = __builtin_amdgcn_mfma_f32_16x16x32_f16(a1, Bf[g][1], z, 0, 0, 0);
                acc[g] = z;
            }
            // dual-pair cell math, 2-wide batched rcp (R15-verified)
            const f32x2 ei0 = {ex2(acc[0][0]), ex2(acc[0][1])};
            const f32x2 ei1 = {ex2(acc[0][2]), ex2(acc[0][3])};
            const f32x2 ef0 = {ex2(acc[1][0]), ex2(acc[1][1])};
            const f32x2 ef1 = {ex2(acc[1][2]), ex2(acc[1][3])};
            const f32x2 eg0 = {ex2(acc[2][0]), ex2(acc[2][1])};
            const f32x2 eg1 = {ex2(acc[2][2]), ex2(acc[2][3])};
            const f32x2 eo0 = {ex2(acc[3][0]), ex2(acc[3][1])};
            const f32x2 eo1 = {ex2(acc[3][2]), ex2(acc[3][3])};
            const f32x2 P0 = ei0 + 1.0f;
            const f32x2 P1 = ei1 + 1.0f;
            const f32x2 p0 = fma2(eg0, P0, P0);        // (1+ei)(1+eg)
            const f32x2 p1 = fma2(eg1, P1, P1);
            const f32x2 w0 = fma2(eg0, NCSC2, CSC2);   // CSC*(1-eg)
            const f32x2 w1 = fma2(eg1, NCSC2, CSC2);
            const f32x2 qw0 = fma2(ef0, w0, w0);       // q*w
            const f32x2 qw1 = fma2(ef1, w1, w1);
            const f32x2 nums0 = fma2(cst[rt][0], p0, qw0);  // CSC*num
            const f32x2 nums1 = fma2(cst[rt][1], p1, qw1);
            const f32x2 pq0 = fma2(ef0, p0, p0);       // p*q
            const f32x2 pq1 = fma2(ef1, p1, p1);
            const f32x2 m1 = pq0 * pq1;
            const f32x2 r1 = {rcp(m1.x), rcp(m1.y)};
            const f32x2 cs0 = nums0 * (r1 * pq1);      // CSC*c'
            const f32x2 cs1 = nums1 * (r1 * pq0);
            cst[rt][0] = cs0;
            cst[rt][1] = cs1;
            const f32x2 ec0 = ex22(cs0);
            const f32x2 ec1 = ex22(cs1);
            const f32x2 Ao0 = eo0 + 1.0f;
            const f32x2 Ao1 = eo1 + 1.0f;
            const f32x2 dn0 = fma2(ec0, Ao0, Ao0);     // (1+eo)(1+ec)
            const f32x2 dn1 = fma2(ec1, Ao1, Ao1);
            const f32x2 om0 = 1.0f - ec0;
            const f32x2 om1 = 1.0f - ec1;
            const f32x2 m2 = dn0 * dn1;
            const f32x2 r2 = {rcp(m2.x), rcp(m2.y)};
            const f32x2 h20 = om0 * (r2 * dn1);
            const f32x2 h21 = om1 * (r2 * dn0);
            const int rb = rt * 16 + quad * 4;
            hbuf[dst][(rb + 0) * HSTR + ncol] = (_Float16)h20.x;
            hbuf[dst][(rb + 1) * HSTR + ncol] = (_Float16)h20.y;
            hbuf[dst][(rb + 2) * HSTR + ncol] = (_Float16)h21.x;
            hbuf[dst][(rb + 3) * HSTR + ncol] = (_Float16)h21.y;
        }
    }

    __syncthreads();  // h(t=4) complete in hbuf[0]

    // Dense(1, relu): 4 threads per row, each sums 16 of the 64 units.
    {
        const int row = tid & 63;           // 0..63
        const int qh  = tid >> 6;           // 0..3
        float s = 0.0f;
#pragma unroll
        for (int j = 0; j < 16; ++j)
            s += (float)hbuf[0][row * HSTR + qh * 16 + j] * wds[qh * 16 + j];
        red[qh][row] = s;
    }
    __syncthreads();
    if (tid < MB) {
        const float r = red[0][tid] + red[1][tid] + red[2][tid] + red[3][tid] + bd[0];
        out[row0 + tid] = fmaxf(r, 0.0f);
    }
}

extern "C" void kernel_launch(void* const* d_in, const int* in_sizes, int n_in,
                              void* d_out, int out_size, void* d_ws, size_t ws_size,
                              hipStream_t stream) {
    const float* x  = (const float*)d_in[0];
    const float* W  = (const float*)d_in[1];
    const float* U  = (const float*)d_in[2];
    const float* b  = (const float*)d_in[3];
    const float* Wd = (const float*)d_in[4];
    const float* bd = (const float*)d_in[5];
    float* out = (float*)d_out;
    const int B = in_sizes[0] / 5;
    const int grid = B / MB;   // 4096 blocks
    lstm_fused<<<grid, NTHREADS, 0, stream>>>(x, W, U, b, Wd, bd, out, B);
}